// Round 5
// baseline (274.494 us; speedup 1.0000x reference)
//
#include <hip/hip_runtime.h>

// FCPlanenet on MI355X (gfx950). fp32 inputs, **fp32 output** [32*9].
// Round 5: device code identical to round 4 (probe-verified MFMA + LUT
// scatter) EXCEPT: k_final writes float (out buffer is fp32 — npz size
// evidence: 1258 B for 288 elems), and the last pooled layer skips the
// h-write (h3 never re-read; pm suffices for k_final).

using bf16x8 = __attribute__((ext_vector_type(8))) __bf16;
using u16x8  = __attribute__((ext_vector_type(8))) unsigned short;
using f32x4  = __attribute__((ext_vector_type(4))) float;

__device__ __forceinline__ unsigned short f2bf(float x) {
  unsigned int u = __float_as_uint(x);
  u += 0x7FFFu + ((u >> 16) & 1u);   // round-to-nearest-even
  return (unsigned short)(u >> 16);
}

__device__ __forceinline__ f32x4 mfma16(bf16x8 a, bf16x8 b, f32x4 c) {
  return __builtin_amdgcn_mfma_f32_16x16x32_bf16(a, b, c, 0, 0, 0);
}

union FragU { unsigned short us[8]; u16x8 u; bf16x8 v; };

// ---------------------------------------------------------------------------
// Probe: discover the value->(row,col) map of our MFMA usage (see round 3).
// ---------------------------------------------------------------------------
__global__ void k_probe(int* __restrict__ lut) {
  const int l = threadIdx.x & 63, g = l >> 4, c = l & 15;
  FragU aI, bk, bn;
#pragma unroll
  for (int j = 0; j < 8; ++j) {
    const int k = g * 8 + j;
    aI.us[j] = (k == c) ? (unsigned short)0x3F80 : (unsigned short)0;  // 1.0 : 0.0
    bk.us[j] = f2bf((float)k);
    bn.us[j] = f2bf((float)c);
  }
  const f32x4 z = {0.f, 0.f, 0.f, 0.f};
  f32x4 d1 = mfma16(aI.v, bk.v, z);
  f32x4 d2 = mfma16(aI.v, bn.v, z);
#pragma unroll
  for (int r = 0; r < 4; ++r) {
    const int row = ((int)(d1[r] + 0.5f)) & 255;
    const int col = ((int)(d2[r] + 0.5f)) & 255;
    lut[(l << 2) + r] = (col << 8) | row;
  }
}

// ---------------------------------------------------------------------------
// Pack W[k][n] (fp32, K x 128) -> frag-ordered bf16.
// slot = (ks*8 + nt)*64 + lane ; lane holds W[ks*32+(lane>>4)*8+j][nt*16+(lane&15)]
// ---------------------------------------------------------------------------
__global__ void k_pack(const float* __restrict__ W, unsigned short* __restrict__ dst,
                       int nslots) {
  int slot = blockIdx.x * blockDim.x + threadIdx.x;
  if (slot >= nslots) return;
  int ks = slot >> 9;
  int rem = slot & 511;
  int nt = rem >> 6, lane = rem & 63;
  int n = nt * 16 + (lane & 15);
  int kb = ks * 32 + ((lane >> 4) << 3);
  FragU fr;
#pragma unroll
  for (int j = 0; j < 8; ++j) fr.us[j] = f2bf(W[(kb + j) * 128 + n]);
  reinterpret_cast<u16x8*>(dst)[slot] = fr.u;
}

// ---------------------------------------------------------------------------
// Layer 0: h = relu(p@Wpos + bpos) @ W0 + b0 (bf16 h, pre-relu), pm per block.
// ---------------------------------------------------------------------------
__global__ __launch_bounds__(256) void k_layer0(
    const float* __restrict__ p, const float* __restrict__ Wpos,
    const float* __restrict__ bpos, const float* __restrict__ b0,
    const unsigned short* __restrict__ Wt0, const int* __restrict__ lut,
    unsigned short* __restrict__ h, float* __restrict__ pm) {
  __shared__ float wls[1024];   // Wpos (3x256 row-major) + bpos (256)
  __shared__ float hs[8192];    // 64 rows x 128 cols, fp32
  __shared__ float addv[128];
  const int t = threadIdx.x, blk = blockIdx.x;
  for (int i = t; i < 1024; i += 256) wls[i] = (i < 768) ? Wpos[i] : bpos[i - 768];

  const int w = t >> 6, lane = t & 63, g = lane >> 4;
  const int row = blk * 64 + w * 16 + (lane & 15);
  const float p0 = p[row * 3 + 0], p1 = p[row * 3 + 1], p2 = p[row * 3 + 2];

  f32x4 acc[8];
#pragma unroll
  for (int nt = 0; nt < 8; ++nt) acc[nt] = f32x4{0.f, 0.f, 0.f, 0.f};
  __syncthreads();

#pragma unroll
  for (int ks = 0; ks < 8; ++ks) {
    FragU a;
    const int kb = ks * 32 + g * 8;
#pragma unroll
    for (int j = 0; j < 8; ++j) {
      const int k = kb + j;
      a.us[j] = f2bf(fmaxf(wls[768 + k] + p0 * wls[k] + p1 * wls[256 + k] + p2 * wls[512 + k], 0.f));
    }
    const bf16x8* Bf = reinterpret_cast<const bf16x8*>(Wt0) + (ks * 512 + lane);
#pragma unroll
    for (int nt = 0; nt < 8; ++nt) acc[nt] = mfma16(a.v, Bf[nt * 64], acc[nt]);
  }

  // scatter acc into LDS via probed LUT
#pragma unroll
  for (int r = 0; r < 4; ++r) {
    const int lv = lut[(lane << 2) + r];
    const int ro = lv & 15, co = (lv >> 8) & 15;
    float* dst = &hs[(w * 16 + ro) * 128 + co];
#pragma unroll
    for (int nt = 0; nt < 8; ++nt) dst[nt * 16] = acc[nt][r];
  }
  if (t < 128) addv[t] = b0[t];
  __syncthreads();

  for (int idx = t; idx < 8192; idx += 256) {
    const int rl = idx >> 7, col = idx & 127;
    h[(size_t)(blk * 64 + rl) * 128 + col] = f2bf(hs[idx] + addv[col]);
  }
  if (t < 128) {
    float m = -3.0e38f;
    for (int rl = 0; rl < 64; ++rl) m = fmaxf(m, hs[rl * 128 + t]);
    pm[blk * 128 + t] = m + addv[t];
  }
}

// ---------------------------------------------------------------------------
// Pooled layer (1..3): h = relu(h) @ Wa + c[b]  (in-place bf16), pm per block.
// write_h=0 for the last layer (h3 never re-read).
// ---------------------------------------------------------------------------
__global__ __launch_bounds__(256) void k_layer(
    const unsigned short* __restrict__ Wta, const float* __restrict__ cvec,
    const int* __restrict__ lut, unsigned short* __restrict__ h,
    float* __restrict__ pm, int write_h) {
  __shared__ float hs[8192];
  __shared__ float addv[128];
  const int t = threadIdx.x, blk = blockIdx.x;
  const int w = t >> 6, lane = t & 63, g = lane >> 4;
  const int row = blk * 64 + w * 16 + (lane & 15);
  const int b = blk >> 7;   // 128 blocks (of 64 pts) per batch of 8192

  f32x4 acc[8];
#pragma unroll
  for (int nt = 0; nt < 8; ++nt) acc[nt] = f32x4{0.f, 0.f, 0.f, 0.f};

  const u16x8* hrow = reinterpret_cast<const u16x8*>(h) + row * 16;
#pragma unroll
  for (int ks = 0; ks < 4; ++ks) {
    FragU a;
    a.u = hrow[ks * 4 + g];
#pragma unroll
    for (int j = 0; j < 8; ++j)
      a.us[j] = (a.us[j] & 0x8000u) ? (unsigned short)0 : a.us[j];  // bf16 relu
    const bf16x8* Bf = reinterpret_cast<const bf16x8*>(Wta) + (ks * 512 + lane);
#pragma unroll
    for (int nt = 0; nt < 8; ++nt) acc[nt] = mfma16(a.v, Bf[nt * 64], acc[nt]);
  }

#pragma unroll
  for (int r = 0; r < 4; ++r) {
    const int lv = lut[(lane << 2) + r];
    const int ro = lv & 15, co = (lv >> 8) & 15;
    float* dst = &hs[(w * 16 + ro) * 128 + co];
#pragma unroll
    for (int nt = 0; nt < 8; ++nt) dst[nt * 16] = acc[nt][r];
  }
  if (t < 128) addv[t] = cvec[b * 128 + t];
  __syncthreads();

  if (write_h) {
    for (int idx = t; idx < 8192; idx += 256) {
      const int rl = idx >> 7, col = idx & 127;
      h[(size_t)(blk * 64 + rl) * 128 + col] = f2bf(hs[idx] + addv[col]);
    }
  }
  if (t < 128) {
    float m = -3.0e38f;
    for (int rl = 0; rl < 64; ++rl) m = fmaxf(m, hs[rl * 128 + t]);
    pm[blk * 128 + t] = m + addv[t];
  }
}

// ---------------------------------------------------------------------------
// Combine: m[b] = max over 128 partials; c[b][n] = relu(m)@Wn[128:256] + bn[n]
// ---------------------------------------------------------------------------
__global__ __launch_bounds__(128) void k_combine(
    const float* __restrict__ pm, const float* __restrict__ Wn,
    const float* __restrict__ bn, float* __restrict__ cout) {
  const int b = blockIdx.x, f = threadIdx.x;
  __shared__ float rm[128];
  float m = -3.0e38f;
  for (int i = 0; i < 128; ++i) m = fmaxf(m, pm[(b * 128 + i) * 128 + f]);
  rm[f] = fmaxf(m, 0.f);
  __syncthreads();
  float s = bn[f];
  for (int q = 0; q < 128; ++q) s += rm[q] * Wn[(128 + q) * 128 + f];
  cout[b * 128 + f] = s;
}

// ---------------------------------------------------------------------------
// Final: g = max over partials; 5-layer head MLP (fp32 VALU); out fp32 [32,9]
// ---------------------------------------------------------------------------
__global__ __launch_bounds__(128) void k_final(
    const float* __restrict__ pm3,
    const float* __restrict__ Wc,  const float* __restrict__ bc,
    const float* __restrict__ Wm0, const float* __restrict__ bm0,
    const float* __restrict__ Wm1, const float* __restrict__ bm1,
    const float* __restrict__ Wm2, const float* __restrict__ bm2,
    const float* __restrict__ Wp,  const float* __restrict__ bp,
    float* __restrict__ out) {
  const int b = blockIdx.x, f = threadIdx.x;
  __shared__ float x[128];
  float m = -3.0e38f;
  for (int i = 0; i < 128; ++i) m = fmaxf(m, pm3[(b * 128 + i) * 128 + f]);
  x[f] = fmaxf(m, 0.f);
  __syncthreads();

  const float* Ws[4] = {Wc, Wm0, Wm1, Wm2};
  const float* bs[4] = {bc, bm0, bm1, bm2};
#pragma unroll
  for (int L = 0; L < 4; ++L) {
    float s = bs[L][f];
    for (int q = 0; q < 128; ++q) s += x[q] * Ws[L][q * 128 + f];
    __syncthreads();
    x[f] = fmaxf(s, 0.f);
    __syncthreads();
  }
  if (f < 9) {
    float s = bp[f];
    for (int q = 0; q < 128; ++q) s += x[q] * Wp[q * 9 + f];
    out[b * 9 + f] = s;    // fp32 output
  }
}

// ---------------------------------------------------------------------------
extern "C" void kernel_launch(void* const* d_in, const int* in_sizes, int n_in,
                              void* d_out, int out_size, void* d_ws, size_t ws_size,
                              hipStream_t stream) {
  // Size-class input mapping: robust to dict-insertion OR alphabetical order.
  const float *p = nullptr, *Wpos = nullptr, *bpos = nullptr;
  const float *Wp = nullptr, *bp = nullptr;
  const float *W256[4] = {nullptr, nullptr, nullptr, nullptr}; int nW256 = 0;
  const float *W128[4] = {nullptr, nullptr, nullptr, nullptr}; int nW128 = 0;
  const float *B128[8] = {nullptr, nullptr, nullptr, nullptr,
                          nullptr, nullptr, nullptr, nullptr}; int nB128 = 0;
  for (int i = 0; i < n_in; ++i) {
    const float* q = (const float*)d_in[i];
    switch (in_sizes[i]) {
      case 786432: p = q; break;                       // p [32,8192,3]
      case 768:    Wpos = q; break;                    // W_pos [3,256]
      case 256:    bpos = q; break;                    // b_pos [256]
      case 1152:   Wp = q; break;                      // Wp [128,9]
      case 9:      bp = q; break;                      // bp [9]
      case 32768:  if (nW256 < 4) W256[nW256++] = q; break;  // W0..W3
      case 16384:  if (nW128 < 4) W128[nW128++] = q; break;  // Wc,Wm0,Wm1,Wm2
      case 128:    if (nB128 < 8) B128[nB128++] = q; break;  // b0..b3,bc,bm0..bm2
      default: break;
    }
  }
  const float *W0 = W256[0], *W1 = W256[1], *W2 = W256[2], *W3 = W256[3];
  const float *Wc = W128[0], *Wm0 = W128[1], *Wm1 = W128[2], *Wm2 = W128[3];
  const float *b0 = B128[0], *b1 = B128[1], *b2 = B128[2], *b3 = B128[3];
  const float *bc = B128[4], *bm0 = B128[5], *bm1 = B128[6], *bm2 = B128[7];
  float* out = (float*)d_out;   // fp32 output

  // ws layout (~66.2 MB total)
  char* ws = (char*)d_ws;
  int*   lut = (int*)ws;                                     // 1 KiB (pad 4 KiB)
  float* pm  = (float*)(ws + 4096);                          // 2 MiB
  float* cv  = (float*)(ws + 4096 + 2097152);                // 16 KiB
  unsigned short* Wt0 = (unsigned short*)(ws + 4096 + 2097152 + 16384);  // 64 KiB
  unsigned short* Wt1 = Wt0 + 32768;                         // 32 KiB each
  unsigned short* Wt2 = Wt1 + 16384;
  unsigned short* Wt3 = Wt2 + 16384;
  unsigned short* h   = Wt3 + 16384;                         // 64 MiB

  k_probe<<<1, 64, 0, stream>>>(lut);
  k_pack<<<16, 256, 0, stream>>>(W0, Wt0, 4096);
  k_pack<<<8, 256, 0, stream>>>(W1, Wt1, 2048);
  k_pack<<<8, 256, 0, stream>>>(W2, Wt2, 2048);
  k_pack<<<8, 256, 0, stream>>>(W3, Wt3, 2048);

  k_layer0<<<4096, 256, 0, stream>>>(p, Wpos, bpos, b0, Wt0, lut, h, pm);
  k_combine<<<32, 128, 0, stream>>>(pm, W1, b1, cv);
  k_layer<<<4096, 256, 0, stream>>>(Wt1, cv, lut, h, pm, 1);
  k_combine<<<32, 128, 0, stream>>>(pm, W2, b2, cv);
  k_layer<<<4096, 256, 0, stream>>>(Wt2, cv, lut, h, pm, 1);
  k_combine<<<32, 128, 0, stream>>>(pm, W3, b3, cv);
  k_layer<<<4096, 256, 0, stream>>>(Wt3, cv, lut, h, pm, 0);
  k_final<<<32, 128, 0, stream>>>(pm, Wc, bc, Wm0, bm0, Wm1, bm1, Wm2, bm2, Wp, bp, out);
}

// Round 6
// 191.257 us; speedup vs baseline: 1.4352x; 1.4352x over previous
//
#include <hip/hip_runtime.h>

// FCPlanenet on MI355X (gfx950). fp32 inputs, fp32 output [32*9].
// Round 6: perf rewrite of the verified round-5 pipeline.
//  - h stored as relu'd bf16 in MFMA-fragment order:
//      h[(tile)*2048 + ks*512 + lane*8 + j], tile=row/16, lane holds
//      row=tile*16+(lane&15), cols ks*32+(lane>>4)*8+j  -> dense 16B/lane
//      loads AND stores.
//  - LDS transpose tile stride 132 floats => 2-way (free) bank access.
//  - C/D map hardcoded (probe-verified R3/R4): col=lane&15, row=(lane>>4)*4+r.
//  - bias folded into acc pre-scatter; relu at store; pm = max(relu(h)) via
//    per-thread 4x8 tile max + shfl_xor reduce.
//  - one pack kernel, split-halves combine/final. 9 dispatches total.

using bf16x8 = __attribute__((ext_vector_type(8))) __bf16;
using u16x8  = __attribute__((ext_vector_type(8))) unsigned short;
using f32x4  = __attribute__((ext_vector_type(4))) float;

__device__ __forceinline__ unsigned short f2bf(float x) {
  unsigned int u = __float_as_uint(x);
  u += 0x7FFFu + ((u >> 16) & 1u);   // RNE
  return (unsigned short)(u >> 16);
}

__device__ __forceinline__ f32x4 mfma16(bf16x8 a, bf16x8 b, f32x4 c) {
  return __builtin_amdgcn_mfma_f32_16x16x32_bf16(a, b, c, 0, 0, 0);
}

union FragU { unsigned short us[8]; u16x8 u; bf16x8 v; };

// ---------------------------------------------------------------------------
// Pack all four W (fp32 KxN, N=128) -> frag-ordered bf16 into one buffer.
// slot = (ks*8 + nt)*64 + lane ; holds W[ks*32+(lane>>4)*8+j][nt*16+(lane&15)]
// blocks 0-15: W0 (4096 slots); 16-23: W1; 24-31: W2; 32-39: W3 (2048 each).
// ---------------------------------------------------------------------------
__global__ __launch_bounds__(256) void k_pack_all(
    const float* __restrict__ W0, const float* __restrict__ W1,
    const float* __restrict__ W2, const float* __restrict__ W3,
    unsigned short* __restrict__ Wt) {
  const int blk = blockIdx.x, t = threadIdx.x;
  const float* src; int slot; unsigned short* dst;
  if (blk < 16)      { src = W0; slot = blk * 256 + t;        dst = Wt; }
  else if (blk < 24) { src = W1; slot = (blk - 16) * 256 + t; dst = Wt + 32768; }
  else if (blk < 32) { src = W2; slot = (blk - 24) * 256 + t; dst = Wt + 49152; }
  else               { src = W3; slot = (blk - 32) * 256 + t; dst = Wt + 65536; }
  const int ks = slot >> 9, rem = slot & 511;
  const int nt = rem >> 6, lane = rem & 63;
  const int n = nt * 16 + (lane & 15);
  const int kb = ks * 32 + ((lane >> 4) << 3);
  FragU fr;
#pragma unroll
  for (int j = 0; j < 8; ++j) fr.us[j] = f2bf(src[(kb + j) * 128 + n]);
  reinterpret_cast<u16x8*>(dst)[slot] = fr.u;
}

// ---------------------------------------------------------------------------
// Shared epilogue (device inline): acc(+bias) -> LDS(132-stride) ->
//   {frag-order bf16 h stores, pm via tile-max + shuffle}.
// ---------------------------------------------------------------------------
__device__ __forceinline__ void epilogue(
    float (&hs)[64 * 132], float (&pmaxs)[4][128], const f32x4 (&acc)[8],
    const float (&bias)[8], int t, int blk, unsigned short* __restrict__ h,
    float* __restrict__ pm, bool write_h) {
  const int w = t >> 6, lane = t & 63, g = lane >> 4, c = lane & 15;
  // scatter: 2 lanes/bank (132-stride)
#pragma unroll
  for (int r = 0; r < 4; ++r) {
    float* dst = &hs[(w * 16 + g * 4 + r) * 132 + c];
#pragma unroll
    for (int nt = 0; nt < 8; ++nt) dst[nt * 16] = acc[nt][r] + bias[nt];
  }
  __syncthreads();

  // pm pass: thread -> rows (t>>4)*4..+3, cols (t&15)*8..+7
  {
    const int rg = t >> 4, cb = t & 15;
    float mx[8];
#pragma unroll
    for (int j = 0; j < 8; ++j) mx[j] = 0.f;   // relu'd max is >= 0
#pragma unroll
    for (int rr = 0; rr < 4; ++rr) {
      const float4* row4 = reinterpret_cast<const float4*>(&hs[(rg * 4 + rr) * 132]);
      const float4 v0 = row4[cb * 2], v1 = row4[cb * 2 + 1];
      mx[0] = fmaxf(mx[0], v0.x); mx[1] = fmaxf(mx[1], v0.y);
      mx[2] = fmaxf(mx[2], v0.z); mx[3] = fmaxf(mx[3], v0.w);
      mx[4] = fmaxf(mx[4], v1.x); mx[5] = fmaxf(mx[5], v1.y);
      mx[6] = fmaxf(mx[6], v1.z); mx[7] = fmaxf(mx[7], v1.w);
    }
#pragma unroll
    for (int j = 0; j < 8; ++j) {
      mx[j] = fmaxf(mx[j], __shfl_xor(mx[j], 16, 64));
      mx[j] = fmaxf(mx[j], __shfl_xor(mx[j], 32, 64));
    }
    if (lane < 16) {
#pragma unroll
      for (int j = 0; j < 8; ++j) pmaxs[w][c * 8 + j] = mx[j];
    }
  }

  // h store: frag-order, dense 16B/lane
  if (write_h) {
    u16x8* hout = reinterpret_cast<u16x8*>(h) + (size_t)blk * 1024;
#pragma unroll
    for (int i = 0; i < 4; ++i) {
      const int s = i * 256 + t;
      const int tl = s >> 8, ks = (s >> 6) & 3, lp = s & 63;
      const int row = tl * 16 + (lp & 15);
      const int c0 = ((lp >> 4) << 3) + ks * 32;
      const float4* row4 = reinterpret_cast<const float4*>(&hs[row * 132]);
      const float4 v0 = row4[c0 >> 2], v1 = row4[(c0 >> 2) + 1];
      FragU fr;
      fr.us[0] = f2bf(fmaxf(v0.x, 0.f)); fr.us[1] = f2bf(fmaxf(v0.y, 0.f));
      fr.us[2] = f2bf(fmaxf(v0.z, 0.f)); fr.us[3] = f2bf(fmaxf(v0.w, 0.f));
      fr.us[4] = f2bf(fmaxf(v1.x, 0.f)); fr.us[5] = f2bf(fmaxf(v1.y, 0.f));
      fr.us[6] = f2bf(fmaxf(v1.z, 0.f)); fr.us[7] = f2bf(fmaxf(v1.w, 0.f));
      hout[tl * 256 + ks * 64 + lp] = fr.u;
    }
  }
  __syncthreads();
  if (t < 128) {
    pm[(size_t)blk * 128 + t] =
        fmaxf(fmaxf(pmaxs[0][t], pmaxs[1][t]), fmaxf(pmaxs[2][t], pmaxs[3][t]));
  }
}

// ---------------------------------------------------------------------------
// Layer 0: h = relu( relu(p@Wpos+bpos) @ W0 + b0 ), pm per block.
// ---------------------------------------------------------------------------
__global__ __launch_bounds__(256) void k_layer0(
    const float* __restrict__ p, const float* __restrict__ Wpos,
    const float* __restrict__ bpos, const float* __restrict__ b0,
    const unsigned short* __restrict__ Wt0, unsigned short* __restrict__ h,
    float* __restrict__ pm) {
  __shared__ float wls[1024];
  __shared__ float hs[64 * 132];
  __shared__ float pmaxs[4][128];
  const int t = threadIdx.x, blk = blockIdx.x;
  for (int i = t; i < 1024; i += 256) wls[i] = (i < 768) ? Wpos[i] : bpos[i - 768];

  const int w = t >> 6, lane = t & 63, g = lane >> 4;
  const int row = blk * 64 + w * 16 + (lane & 15);
  const float p0 = p[row * 3 + 0], p1 = p[row * 3 + 1], p2 = p[row * 3 + 2];

  float bias[8];
#pragma unroll
  for (int nt = 0; nt < 8; ++nt) bias[nt] = b0[nt * 16 + (lane & 15)];

  f32x4 acc[8];
#pragma unroll
  for (int nt = 0; nt < 8; ++nt) acc[nt] = f32x4{0.f, 0.f, 0.f, 0.f};
  __syncthreads();

#pragma unroll
  for (int ks = 0; ks < 8; ++ks) {
    FragU a;
    const int kb = ks * 32 + g * 8;
#pragma unroll
    for (int j = 0; j < 8; ++j) {
      const int k = kb + j;
      a.us[j] = f2bf(fmaxf(wls[768 + k] + p0 * wls[k] + p1 * wls[256 + k] + p2 * wls[512 + k], 0.f));
    }
    const bf16x8* Bf = reinterpret_cast<const bf16x8*>(Wt0) + (ks * 512 + lane);
#pragma unroll
    for (int nt = 0; nt < 8; ++nt) acc[nt] = mfma16(a.v, Bf[nt * 64], acc[nt]);
  }
  epilogue(hs, pmaxs, acc, bias, t, blk, h, pm, true);
}

// ---------------------------------------------------------------------------
// Pooled layer: h = relu( h @ Wa + c[b] ) (h already relu'd bf16, frag order)
// ---------------------------------------------------------------------------
__global__ __launch_bounds__(256) void k_layer(
    const unsigned short* __restrict__ Wta, const float* __restrict__ cvec,
    unsigned short* __restrict__ h, float* __restrict__ pm, int write_h) {
  __shared__ float hs[64 * 132];
  __shared__ float pmaxs[4][128];
  const int t = threadIdx.x, blk = blockIdx.x;
  const int w = t >> 6, lane = t & 63;
  const int b = blk >> 7;

  float bias[8];
#pragma unroll
  for (int nt = 0; nt < 8; ++nt) bias[nt] = cvec[b * 128 + nt * 16 + (lane & 15)];

  f32x4 acc[8];
#pragma unroll
  for (int nt = 0; nt < 8; ++nt) acc[nt] = f32x4{0.f, 0.f, 0.f, 0.f};

  const u16x8* hA = reinterpret_cast<const u16x8*>(h) + ((size_t)(blk * 4 + w)) * 256;
#pragma unroll
  for (int ks = 0; ks < 4; ++ks) {
    FragU a;
    a.u = hA[ks * 64 + lane];
    const bf16x8* Bf = reinterpret_cast<const bf16x8*>(Wta) + (ks * 512 + lane);
#pragma unroll
    for (int nt = 0; nt < 8; ++nt) acc[nt] = mfma16(a.v, Bf[nt * 64], acc[nt]);
  }
  epilogue(hs, pmaxs, acc, bias, t, blk, h, pm, write_h != 0);
}

// ---------------------------------------------------------------------------
// Combine: m[b] = max over 128 partials; c[b][n] = relu(m)@Wn[128:256] + bn
// ---------------------------------------------------------------------------
__global__ __launch_bounds__(256) void k_combine(
    const float* __restrict__ pm, const float* __restrict__ Wn,
    const float* __restrict__ bn, float* __restrict__ cout) {
  const int b = blockIdx.x, t = threadIdx.x;
  const int f = t & 127, half = t >> 7;
  __shared__ float part[2][128];
  __shared__ float rm[128];
  float m = 0.f;   // pm values are relu'd maxima (>=0)
  for (int i = half * 64; i < half * 64 + 64; ++i)
    m = fmaxf(m, pm[(size_t)(b * 128 + i) * 128 + f]);
  part[half][f] = m;
  __syncthreads();
  if (t < 128) rm[f] = fmaxf(part[0][f], part[1][f]);
  __syncthreads();
  float s = 0.f;
  for (int q = half * 64; q < half * 64 + 64; ++q)
    s += rm[q] * Wn[(128 + q) * 128 + f];
  part[half][f] = s;
  __syncthreads();
  if (t < 128) cout[b * 128 + f] = part[0][f] + part[1][f] + bn[f];
}

// ---------------------------------------------------------------------------
// Final: g = max over partials; 5-layer head MLP (fp32); out fp32 [32,9]
// ---------------------------------------------------------------------------
__global__ __launch_bounds__(256) void k_final(
    const float* __restrict__ pm3,
    const float* __restrict__ Wc,  const float* __restrict__ bc,
    const float* __restrict__ Wm0, const float* __restrict__ bm0,
    const float* __restrict__ Wm1, const float* __restrict__ bm1,
    const float* __restrict__ Wm2, const float* __restrict__ bm2,
    const float* __restrict__ Wp,  const float* __restrict__ bp,
    float* __restrict__ out) {
  const int b = blockIdx.x, t = threadIdx.x;
  const int f = t & 127, half = t >> 7;
  __shared__ float part[2][128];
  __shared__ float x[128];
  float m = 0.f;
  for (int i = half * 64; i < half * 64 + 64; ++i)
    m = fmaxf(m, pm3[(size_t)(b * 128 + i) * 128 + f]);
  part[half][f] = m;
  __syncthreads();
  if (t < 128) x[f] = fmaxf(part[0][f], part[1][f]);
  __syncthreads();

  const float* Ws[4] = {Wc, Wm0, Wm1, Wm2};
  const float* bs[4] = {bc, bm0, bm1, bm2};
#pragma unroll
  for (int L = 0; L < 4; ++L) {
    float s = 0.f;
    for (int q = half * 64; q < half * 64 + 64; ++q)
      s += x[q] * Ws[L][q * 128 + f];
    part[half][f] = s;
    __syncthreads();
    if (t < 128) x[f] = fmaxf(part[0][f] + part[1][f] + bs[L][f], 0.f);
    __syncthreads();
  }
  if (t < 9) {
    float s = bp[t];
    for (int q = 0; q < 128; ++q) s += x[q] * Wp[q * 9 + t];
    out[b * 9 + t] = s;
  }
}

// ---------------------------------------------------------------------------
extern "C" void kernel_launch(void* const* d_in, const int* in_sizes, int n_in,
                              void* d_out, int out_size, void* d_ws, size_t ws_size,
                              hipStream_t stream) {
  // Size-class input mapping (order-robust; verified round 5).
  const float *p = nullptr, *Wpos = nullptr, *bpos = nullptr;
  const float *Wp = nullptr, *bp = nullptr;
  const float *W256[4] = {}; int nW256 = 0;
  const float *W128[4] = {}; int nW128 = 0;
  const float *B128[8] = {}; int nB128 = 0;
  for (int i = 0; i < n_in; ++i) {
    const float* q = (const float*)d_in[i];
    switch (in_sizes[i]) {
      case 786432: p = q; break;
      case 768:    Wpos = q; break;
      case 256:    bpos = q; break;
      case 1152:   Wp = q; break;
      case 9:      bp = q; break;
      case 32768:  if (nW256 < 4) W256[nW256++] = q; break;
      case 16384:  if (nW128 < 4) W128[nW128++] = q; break;
      case 128:    if (nB128 < 8) B128[nB128++] = q; break;
      default: break;
    }
  }
  const float *W0 = W256[0], *W1 = W256[1], *W2 = W256[2], *W3 = W256[3];
  const float *Wc = W128[0], *Wm0 = W128[1], *Wm1 = W128[2], *Wm2 = W128[3];
  const float *b0 = B128[0], *b1 = B128[1], *b2 = B128[2], *b3 = B128[3];
  const float *bc = B128[4], *bm0 = B128[5], *bm1 = B128[6], *bm2 = B128[7];
  float* out = (float*)d_out;

  // ws layout (~66.2 MB)
  char* ws = (char*)d_ws;
  float* pm = (float*)ws;                                    // 2 MiB
  float* cv = (float*)(ws + 2097152);                        // 16 KiB
  unsigned short* Wt = (unsigned short*)(ws + 2097152 + 16384);  // 160 KiB
  unsigned short* Wt0 = Wt;
  unsigned short* Wt1 = Wt + 32768;
  unsigned short* Wt2 = Wt + 49152;
  unsigned short* Wt3 = Wt + 65536;
  unsigned short* h = Wt + 81920;                            // 64 MiB

  k_pack_all<<<40, 256, 0, stream>>>(W0, W1, W2, W3, Wt);
  k_layer0<<<4096, 256, 0, stream>>>(p, Wpos, bpos, b0, Wt0, h, pm);
  k_combine<<<32, 256, 0, stream>>>(pm, W1, b1, cv);
  k_layer<<<4096, 256, 0, stream>>>(Wt1, cv, h, pm, 1);
  k_combine<<<32, 256, 0, stream>>>(pm, W2, b2, cv);
  k_layer<<<4096, 256, 0, stream>>>(Wt2, cv, h, pm, 1);
  k_combine<<<32, 256, 0, stream>>>(pm, W3, b3, cv);
  k_layer<<<4096, 256, 0, stream>>>(Wt3, cv, h, pm, 0);
  k_final<<<32, 256, 0, stream>>>(pm, Wc, bc, Wm0, bm0, Wm1, bm1, Wm2, bm2, Wp, bp, out);
}